// Round 5
// baseline (336.574 us; speedup 1.0000x reference)
//
#include <hip/hip_runtime.h>

// LSTM_67980742362036: 2-layer LSTM (B=4096, T=200, I=32, H=6) + linear head.
//
// R5: SPLIT into proj_kernel (x-projection, massively parallel, xp -> d_ws)
// + scan_kernel (R4-style readlane/DPP scan, xp streamed from global with a
// 2-deep rotating prefetch). Motivation: R2-R4 changed the scan chain
// structurally (barriers->none, bpermute->DPP, spills->none) yet dur pinned
// at ~170 us; fused dispatches can't attribute time between projection and
// scan. Split gives per-phase dur/VALUBusy/occupancy from rocprof.
// Fallback: if ws_size < 82 MB, run the retained R4 fused kernel.

#define BATCH 4096
#define TLEN  200
#define ISZ   32
#define HSZ   6
#define GSZ   24              // 4*H
#define XPT   208             // padded rows per batch in ws (rows 200..207 garbage)
#define XPB   (XPT * GSZ)     // dwords per batch in ws

__device__ __forceinline__ float fast_sig(float x) {
    return __builtin_amdgcn_rcpf(1.0f + __expf(-x));
}
__device__ __forceinline__ float rl(float v, int l) {
    return __int_as_float(__builtin_amdgcn_readlane(__float_as_int(v), l));
}
template <int CTRL>
__device__ __forceinline__ float qperm(float v) {
    return __int_as_float(__builtin_amdgcn_mov_dpp(__float_as_int(v), CTRL, 0xf, 0xf, true));
}

// ------------------------ kernel 1: input projection ------------------------
// xp[b][t][r] = bih0[r]+bhh0[r] + sum_k Wih0[r,k]*x[b,t,k]
// grid (4, BATCH) x 64: lane = t within a 64-row tile. 16384 waves.
__global__ __launch_bounds__(64) void proj_kernel(
    const float* __restrict__ x, const float* __restrict__ Wih0,
    const float* __restrict__ bih0, const float* __restrict__ bhh0,
    float* __restrict__ xp)
{
    const int lane = threadIdx.x;
    const int t    = blockIdx.x * 64 + lane;          // [0,256)
    const int b    = blockIdx.y;
    const int tc   = min(t, TLEN - 1);
    const float4* xrow = (const float4*)(x + ((size_t)b * TLEN + tc) * ISZ);
    float* orow = xp + (size_t)b * XPB + (size_t)tc * GSZ;

    // 3 row-groups x 2 K-halves: register-lean (acc[8] + xr[4] live), no spill.
#pragma unroll
    for (int grp = 0; grp < 3; ++grp) {
        float acc[8];
#pragma unroll
        for (int rr = 0; rr < 8; ++rr) acc[rr] = bih0[grp * 8 + rr] + bhh0[grp * 8 + rr];
#pragma unroll
        for (int kh = 0; kh < 2; ++kh) {
            float4 xr[4];
#pragma unroll
            for (int q = 0; q < 4; ++q) xr[q] = xrow[4 * kh + q];
#pragma unroll
            for (int rr = 0; rr < 8; ++rr) {
                const float4* wrow = (const float4*)(Wih0 + (grp * 8 + rr) * ISZ + kh * 16);
#pragma unroll
                for (int q = 0; q < 4; ++q) {
                    float4 w = wrow[q];
                    acc[rr] += w.x * xr[q].x + w.y * xr[q].y + w.z * xr[q].z + w.w * xr[q].w;
                }
            }
        }
        if (t < TLEN) {
            *(float4*)&orow[8 * grp]     = make_float4(acc[0], acc[1], acc[2], acc[3]);
            *(float4*)&orow[8 * grp + 4] = make_float4(acc[4], acc[5], acc[6], acc[7]);
        }
    }
}

// --------------------------- kernel 2: the scan -----------------------------
// One wave per batch element. Lane = half*32 + 4*unit + gate (i,f,g,o / quad).
// L0 on lanes 0..23 computes step kg; L1 on lanes 32..55 computes step kg-1
// (both consume h1[kg-1]). xp streamed from global, 2 rows ahead.
__global__ __launch_bounds__(64) void scan_kernel(
    const float* __restrict__ xp,
    const float* __restrict__ Whh0,
    const float* __restrict__ Wih1, const float* __restrict__ Whh1,
    const float* __restrict__ bih1, const float* __restrict__ bhh1,
    const float* __restrict__ Wlin, const float* __restrict__ blin,
    float* __restrict__ out)
{
    const int lane = threadIdx.x;
    const int b    = blockIdx.x;

    const bool loHalf = (lane < 32);
    const int  p  = lane & 3;
    const int  jq = (lane & 31) >> 2;
    const int  j  = (jq < HSZ) ? jq : 0;       // idle quads alias unit 0
    const int  r  = 6 * p + j;                 // gate row in W order

    float WA[HSZ], WB[HSZ];
    float base1 = 0.0f;
#pragma unroll
    for (int k = 0; k < HSZ; ++k) { WA[k] = 0.0f; WB[k] = 0.0f; }
    if (loHalf) {
#pragma unroll
        for (int k = 0; k < HSZ; ++k) WA[k] = Whh0[r * HSZ + k];
    } else {
#pragma unroll
        for (int k = 0; k < HSZ; ++k) { WA[k] = Wih1[r * HSZ + k]; WB[k] = Whh1[r * HSZ + k]; }
        base1 = bih1[r] + bhh1[r];
    }
    const float mg  = (p == 2) ? 2.0f : 1.0f;   // cell gate -> tanh via sig
    const float sg  = (p == 2) ? 2.0f : 1.0f;
    const float tgc = (p == 2) ? -1.0f : 0.0f;

    const float* xq = xp + (size_t)b * XPB + r;   // row t at xq[t*GSZ]

    float c = 0.0f, h = 0.0f;                   // quad-replicated state

    // rotating prefetch: rows 0,1,2 in flight before the loop
    float x0 = xq[0];
    float x1 = xq[GSZ];
    float x2 = xq[2 * GSZ];

    // peeled kg==0: h1=h2=0; L1 must stay zero (phantom step)
    {
        const float g  = loHalf ? x0 : base1;
        const float a  = fmaf(sg, fast_sig(mg * g), tgc);
        const float iq = qperm<0x00>(a);
        const float gq = qperm<0xAA>(a);
        const float oq = qperm<0xFF>(a);
        const float cn = iq * gq;
        const float th = fmaf(2.0f, fast_sig(2.0f * cn), -1.0f);
        const float hn = oq * th;
        c = loHalf ? cn : 0.0f;
        h = loHalf ? hn : 0.0f;
    }

    // it = kg = 1..200; at it=200 L0 consumes garbage row 200 (never read on),
    // L1 computes its final step 199. Prefetch touches rows <= 202 (< 208).
    for (int it = 1; it <= TLEN; ++it) {
        const float h10 = rl(h, 0),  h11 = rl(h, 4),  h12 = rl(h, 8);
        const float h13 = rl(h, 12), h14 = rl(h, 16), h15 = rl(h, 20);
        const float h20 = rl(h, 32), h21 = rl(h, 36), h22 = rl(h, 40);
        const float h23 = rl(h, 44), h24 = rl(h, 48), h25 = rl(h, 52);

        const float xnew = xq[(it + 2) * GSZ];   // 2-deep prefetch

        const float g0 = loHalf ? x1 : base1;
        float a0 = fmaf(WA[0], h10, fmaf(WA[2], h12, fmaf(WA[4], h14, g0)));
        float a1 = fmaf(WA[1], h11, fmaf(WA[3], h13, WA[5] * h15));
        float b0 = fmaf(WB[0], h20, fmaf(WB[2], h22, WB[4] * h24));
        float b1 = fmaf(WB[1], h21, fmaf(WB[3], h23, WB[5] * h25));
        const float g = (a0 + a1) + (b0 + b1);
        const float a = fmaf(sg, fast_sig(mg * g), tgc);

        const float iq = qperm<0x00>(a);
        const float fq = qperm<0x55>(a);
        const float gq = qperm<0xAA>(a);
        const float oq = qperm<0xFF>(a);

        c = fmaf(fq, c, iq * gq);
        const float th = fmaf(2.0f, fast_sig(2.0f * c), -1.0f);
        h = oq * th;

        x1 = x2; x2 = xnew;
    }

    float s = blin[0];
#pragma unroll
    for (int k = 0; k < HSZ; ++k) s = fmaf(Wlin[k], rl(h, 32 + 4 * k), s);
    if (lane == 0) out[b] = s;
}

// ------------------- fallback: R4 fused kernel (ws too small) ----------------
#define TCH   64
#define XPITCH 28
#define XROWS (TCH + 1)

__global__ void __launch_bounds__(64)
lstm_fused(
    const float* __restrict__ x,
    const float* __restrict__ Wih0, const float* __restrict__ Whh0,
    const float* __restrict__ bih0, const float* __restrict__ bhh0,
    const float* __restrict__ Wih1, const float* __restrict__ Whh1,
    const float* __restrict__ bih1, const float* __restrict__ bhh1,
    const float* __restrict__ Wlin, const float* __restrict__ blin,
    float* __restrict__ out)
{
    __shared__ __align__(16) float xp_lds[XROWS * XPITCH];

    const int lane = threadIdx.x;
    const int b    = blockIdx.x;

    const bool loHalf = (lane < 32);
    const int  p  = lane & 3;
    const int  jq = (lane & 31) >> 2;
    const int  j  = (jq < HSZ) ? jq : 0;
    const int  r  = 6 * p + j;

    float WA[HSZ], WB[HSZ];
    float base1 = 0.0f;
#pragma unroll
    for (int k = 0; k < HSZ; ++k) { WA[k] = 0.0f; WB[k] = 0.0f; }
    if (loHalf) {
#pragma unroll
        for (int k = 0; k < HSZ; ++k) WA[k] = Whh0[r * HSZ + k];
    } else {
#pragma unroll
        for (int k = 0; k < HSZ; ++k) { WA[k] = Wih1[r * HSZ + k]; WB[k] = Whh1[r * HSZ + k]; }
        base1 = bih1[r] + bhh1[r];
    }
    const float mg  = (p == 2) ? 2.0f : 1.0f;
    const float sg  = (p == 2) ? 2.0f : 1.0f;
    const float tgc = (p == 2) ? -1.0f : 0.0f;

    float c = 0.0f, h = 0.0f;

    for (int t0 = 0; t0 < TLEN; t0 += TCH) {
        const int tcl = min(TCH, TLEN - t0);
        {
            const int tIdx = min(t0 + lane, TLEN - 1);
            const float4* xrow = (const float4*)(x + ((size_t)b * TLEN + tIdx) * ISZ);
#pragma unroll
            for (int grp = 0; grp < 3; ++grp) {
                float acc[8];
#pragma unroll
                for (int rr = 0; rr < 8; ++rr)
                    acc[rr] = bih0[grp * 8 + rr] + bhh0[grp * 8 + rr];
#pragma unroll
                for (int kh = 0; kh < 2; ++kh) {
                    float4 xr[4];
#pragma unroll
                    for (int q = 0; q < 4; ++q) xr[q] = xrow[4 * kh + q];
#pragma unroll
                    for (int rr = 0; rr < 8; ++rr) {
                        const float4* wrow =
                            (const float4*)(Wih0 + (grp * 8 + rr) * ISZ + kh * 16);
#pragma unroll
                        for (int q = 0; q < 4; ++q) {
                            float4 w = wrow[q];
                            acc[rr] += w.x * xr[q].x + w.y * xr[q].y
                                     + w.z * xr[q].z + w.w * xr[q].w;
                        }
                    }
                }
                *(float4*)&xp_lds[lane * XPITCH + 8 * grp] =
                    make_float4(acc[0], acc[1], acc[2], acc[3]);
                *(float4*)&xp_lds[lane * XPITCH + 8 * grp + 4] =
                    make_float4(acc[4], acc[5], acc[6], acc[7]);
            }
        }

        const bool lastChunk = (t0 + TCH >= TLEN);
        const int  iters = tcl + (lastChunk ? 1 : 0);
        float xp_cur = xp_lds[r];
        int   it0 = 0;

        if (t0 == 0) {
            const float g  = loHalf ? xp_cur : base1;
            const float a  = fmaf(sg, fast_sig(mg * g), tgc);
            const float iq = qperm<0x00>(a);
            const float gq = qperm<0xAA>(a);
            const float oq = qperm<0xFF>(a);
            const float cn = iq * gq;
            const float th = fmaf(2.0f, fast_sig(2.0f * cn), -1.0f);
            const float hn = oq * th;
            c = loHalf ? cn : 0.0f;
            h = loHalf ? hn : 0.0f;
            xp_cur = xp_lds[XPITCH + r];
            it0 = 1;
        }

        for (int it = it0; it < iters; ++it) {
            const float h10 = rl(h, 0),  h11 = rl(h, 4),  h12 = rl(h, 8);
            const float h13 = rl(h, 12), h14 = rl(h, 16), h15 = rl(h, 20);
            const float h20 = rl(h, 32), h21 = rl(h, 36), h22 = rl(h, 40);
            const float h23 = rl(h, 44), h24 = rl(h, 48), h25 = rl(h, 52);

            const float xp_nxt = xp_lds[(it + 1) * XPITCH + r];

            const float g0 = loHalf ? xp_cur : base1;
            float a0 = fmaf(WA[0], h10, fmaf(WA[2], h12, fmaf(WA[4], h14, g0)));
            float a1 = fmaf(WA[1], h11, fmaf(WA[3], h13, WA[5] * h15));
            float b0 = fmaf(WB[0], h20, fmaf(WB[2], h22, WB[4] * h24));
            float b1 = fmaf(WB[1], h21, fmaf(WB[3], h23, WB[5] * h25));
            const float g = (a0 + a1) + (b0 + b1);
            const float a = fmaf(sg, fast_sig(mg * g), tgc);

            const float iq = qperm<0x00>(a);
            const float fq = qperm<0x55>(a);
            const float gq = qperm<0xAA>(a);
            const float oq = qperm<0xFF>(a);

            c = fmaf(fq, c, iq * gq);
            const float th = fmaf(2.0f, fast_sig(2.0f * c), -1.0f);
            h = oq * th;

            xp_cur = xp_nxt;
        }
    }

    float s = blin[0];
#pragma unroll
    for (int k = 0; k < HSZ; ++k) s = fmaf(Wlin[k], rl(h, 32 + 4 * k), s);
    if (lane == 0) out[b] = s;
}

extern "C" void kernel_launch(void* const* d_in, const int* in_sizes, int n_in,
                              void* d_out, int out_size, void* d_ws, size_t ws_size,
                              hipStream_t stream) {
    const float* x    = (const float*)d_in[0];
    const float* Wih0 = (const float*)d_in[1];
    const float* Whh0 = (const float*)d_in[2];
    const float* bih0 = (const float*)d_in[3];
    const float* bhh0 = (const float*)d_in[4];
    const float* Wih1 = (const float*)d_in[5];
    const float* Whh1 = (const float*)d_in[6];
    const float* bih1 = (const float*)d_in[7];
    const float* bhh1 = (const float*)d_in[8];
    const float* Wlin = (const float*)d_in[9];
    const float* blin = (const float*)d_in[10];
    float* out = (float*)d_out;

    const size_t need = (size_t)BATCH * XPB * sizeof(float);  // ~81.8 MB
    if (ws_size >= need) {
        float* xp = (float*)d_ws;
        proj_kernel<<<dim3(4, BATCH), 64, 0, stream>>>(x, Wih0, bih0, bhh0, xp);
        scan_kernel<<<BATCH, 64, 0, stream>>>(xp, Whh0, Wih1, Whh1, bih1, bhh1,
                                              Wlin, blin, out);
    } else {
        lstm_fused<<<BATCH, 64, 0, stream>>>(x, Wih0, Whh0, bih0, bhh0,
                                             Wih1, Whh1, bih1, bhh1,
                                             Wlin, blin, out);
    }
}

// Round 6
// 294.557 us; speedup vs baseline: 1.1426x; 1.1426x over previous
//
#include <hip/hip_runtime.h>

// LSTM_67980742362036: 2-layer LSTM (B=4096, T=200, I=32, H=6) + linear head.
//
// R6: attack the two measured sinks from R5's split attribution:
//  - proj was write-layout-bound: xp[t][r] rows are 96 B = 1.5 cache lines ->
//    partial-line RMW, WRITE_SIZE 124 MB vs 78.6 ideal, ~1 TB/s effective.
//    Fix: TRANSPOSED xp[b][r][t] (t padded to 208); stores are 64x4 B
//    contiguous per wave = full 256-B segments. 256-thread blocks.
//  - scan's global xp gather had only a 2-deep prefetch vs ~L3 latency.
//    Fix: row-contiguous per-lane streams (each 64-B line serves 16 iters)
//    + 4-deep rotating register prefetch. 4 batches per 256-thread block.
// Scan body keeps the R4 readlane/DPP form (~50 VALU/iter, no barriers).

#define BATCH 4096
#define TLEN  200
#define ISZ   32
#define HSZ   6
#define GSZ   24              // 4*H
#define XPT   208             // padded t-extent per row (rows 200..207 junk)
#define XPB   (GSZ * XPT)     // dwords per batch in ws (4992)

__device__ __forceinline__ float fast_sig(float x) {
    return __builtin_amdgcn_rcpf(1.0f + __expf(-x));
}
__device__ __forceinline__ float rl(float v, int l) {
    return __int_as_float(__builtin_amdgcn_readlane(__float_as_int(v), l));
}
template <int CTRL>
__device__ __forceinline__ float qperm(float v) {
    return __int_as_float(__builtin_amdgcn_mov_dpp(__float_as_int(v), CTRL, 0xf, 0xf, true));
}

// ------------------------ kernel 1: input projection ------------------------
// xp[b][r][t] = bih0[r]+bhh0[r] + sum_k Wih0[r,k]*x[b,t,k]
// grid BATCH x 256 (4 waves): thread t covers timestep t (0..255, clamped).
// Stores: per row r, 64 lanes write 4 B each, contiguous -> full-line writes.
__global__ __launch_bounds__(256) void proj_kernel(
    const float* __restrict__ x, const float* __restrict__ Wih0,
    const float* __restrict__ bih0, const float* __restrict__ bhh0,
    float* __restrict__ xp)
{
    const int t  = threadIdx.x;               // 0..255
    const int b  = blockIdx.x;
    const int tc = min(t, TLEN - 1);          // clamp; rows 200..207 get junk
    const float4* xrow = (const float4*)(x + ((size_t)b * TLEN + tc) * ISZ);
    float* xpb = xp + (size_t)b * XPB;

    // 3 row-groups x 2 K-halves: register-lean (acc[8] + xr[4] live), no spill.
#pragma unroll
    for (int grp = 0; grp < 3; ++grp) {
        float acc[8];
#pragma unroll
        for (int rr = 0; rr < 8; ++rr) acc[rr] = bih0[grp * 8 + rr] + bhh0[grp * 8 + rr];
#pragma unroll
        for (int kh = 0; kh < 2; ++kh) {
            float4 xr[4];
#pragma unroll
            for (int q = 0; q < 4; ++q) xr[q] = xrow[4 * kh + q];
#pragma unroll
            for (int rr = 0; rr < 8; ++rr) {
                const float4* wrow = (const float4*)(Wih0 + (grp * 8 + rr) * ISZ + kh * 16);
#pragma unroll
                for (int q = 0; q < 4; ++q) {
                    float4 w = wrow[q];
                    acc[rr] += w.x * xr[q].x + w.y * xr[q].y + w.z * xr[q].z + w.w * xr[q].w;
                }
            }
        }
        if (t < XPT) {                         // t=208..255 would clobber next row
#pragma unroll
            for (int rr = 0; rr < 8; ++rr)
                xpb[(size_t)(grp * 8 + rr) * XPT + t] = acc[rr];
        }
    }
}

// --------------------------- kernel 2: the scan -----------------------------
// grid (BATCH/4) x 256: wave w handles batch 4*blockIdx+w. Lane layout within
// a wave: half*32 + 4*unit + gate (i,f,g,o per quad). L0 on lanes 0..23 does
// step kg, L1 on lanes 32..55 does step kg-1 (both consume h1[kg-1]).
// xp row-streams per lane, 4-deep rotating prefetch.
__global__ __launch_bounds__(256) void scan_kernel(
    const float* __restrict__ xp,
    const float* __restrict__ Whh0,
    const float* __restrict__ Wih1, const float* __restrict__ Whh1,
    const float* __restrict__ bih1, const float* __restrict__ bhh1,
    const float* __restrict__ Wlin, const float* __restrict__ blin,
    float* __restrict__ out)
{
    const int lane = threadIdx.x & 63;
    const int b    = blockIdx.x * 4 + (threadIdx.x >> 6);

    const bool loHalf = (lane < 32);
    const int  p  = lane & 3;
    const int  jq = (lane & 31) >> 2;
    const int  j  = (jq < HSZ) ? jq : 0;       // idle quads alias unit 0
    const int  r  = 6 * p + j;                 // gate row in W order

    float WA[HSZ], WB[HSZ];
    float base1 = 0.0f;
#pragma unroll
    for (int k = 0; k < HSZ; ++k) { WA[k] = 0.0f; WB[k] = 0.0f; }
    if (loHalf) {
#pragma unroll
        for (int k = 0; k < HSZ; ++k) WA[k] = Whh0[r * HSZ + k];
    } else {
#pragma unroll
        for (int k = 0; k < HSZ; ++k) { WA[k] = Wih1[r * HSZ + k]; WB[k] = Whh1[r * HSZ + k]; }
        base1 = bih1[r] + bhh1[r];
    }
    const float mg  = (p == 2) ? 2.0f : 1.0f;   // cell gate -> tanh via sig
    const float sg  = (p == 2) ? 2.0f : 1.0f;
    const float tgc = (p == 2) ? -1.0f : 0.0f;

    // per-lane contiguous stream: xq[t] = xp[b][r][t]
    const float* xq = xp + (size_t)b * XPB + (size_t)r * XPT;

    float c = 0.0f, h = 0.0f;                   // quad-replicated state

    // 4-deep rotating prefetch: t = 0..3 in flight
    float x0 = xq[0];
    float x1 = xq[1];
    float x2 = xq[2];
    float x3 = xq[3];

    // peeled kg==0: h1=h2=0; L1 must stay zero (phantom step)
    {
        const float g  = loHalf ? x0 : base1;
        const float a  = fmaf(sg, fast_sig(mg * g), tgc);
        const float iq = qperm<0x00>(a);
        const float gq = qperm<0xAA>(a);
        const float oq = qperm<0xFF>(a);
        const float cn = iq * gq;
        const float th = fmaf(2.0f, fast_sig(2.0f * cn), -1.0f);
        const float hn = oq * th;
        c = loHalf ? cn : 0.0f;
        h = loHalf ? hn : 0.0f;
    }

    // it = kg = 1..200. At it=200 L0 consumes junk row t=200 (its state is
    // never read afterwards); L1 computes its real final step 199.
    // Prefetch touches t <= 203 < 208.
    for (int it = 1; it <= TLEN; ++it) {
        const float h10 = rl(h, 0),  h11 = rl(h, 4),  h12 = rl(h, 8);
        const float h13 = rl(h, 12), h14 = rl(h, 16), h15 = rl(h, 20);
        const float h20 = rl(h, 32), h21 = rl(h, 36), h22 = rl(h, 40);
        const float h23 = rl(h, 44), h24 = rl(h, 48), h25 = rl(h, 52);

        const float xnew = xq[it + 3];          // 4-deep prefetch

        const float g0 = loHalf ? x1 : base1;   // x1 = xp row t=it
        float a0 = fmaf(WA[0], h10, fmaf(WA[2], h12, fmaf(WA[4], h14, g0)));
        float a1 = fmaf(WA[1], h11, fmaf(WA[3], h13, WA[5] * h15));
        float b0 = fmaf(WB[0], h20, fmaf(WB[2], h22, WB[4] * h24));
        float b1 = fmaf(WB[1], h21, fmaf(WB[3], h23, WB[5] * h25));
        const float g = (a0 + a1) + (b0 + b1);
        const float a = fmaf(sg, fast_sig(mg * g), tgc);

        const float iq = qperm<0x00>(a);
        const float fq = qperm<0x55>(a);
        const float gq = qperm<0xAA>(a);
        const float oq = qperm<0xFF>(a);

        c = fmaf(fq, c, iq * gq);
        const float th = fmaf(2.0f, fast_sig(2.0f * c), -1.0f);
        h = oq * th;

        x1 = x2; x2 = x3; x3 = xnew;
    }

    float s = blin[0];
#pragma unroll
    for (int k = 0; k < HSZ; ++k) s = fmaf(Wlin[k], rl(h, 32 + 4 * k), s);
    if (lane == 0) out[b] = s;
}

// ------------------- fallback: R4 fused kernel (ws too small) ----------------
#define TCH   64
#define XPITCH 28
#define XROWS (TCH + 1)

__global__ void __launch_bounds__(64)
lstm_fused(
    const float* __restrict__ x,
    const float* __restrict__ Wih0, const float* __restrict__ Whh0,
    const float* __restrict__ bih0, const float* __restrict__ bhh0,
    const float* __restrict__ Wih1, const float* __restrict__ Whh1,
    const float* __restrict__ bih1, const float* __restrict__ bhh1,
    const float* __restrict__ Wlin, const float* __restrict__ blin,
    float* __restrict__ out)
{
    __shared__ __align__(16) float xp_lds[XROWS * XPITCH];

    const int lane = threadIdx.x;
    const int b    = blockIdx.x;

    const bool loHalf = (lane < 32);
    const int  p  = lane & 3;
    const int  jq = (lane & 31) >> 2;
    const int  j  = (jq < HSZ) ? jq : 0;
    const int  r  = 6 * p + j;

    float WA[HSZ], WB[HSZ];
    float base1 = 0.0f;
#pragma unroll
    for (int k = 0; k < HSZ; ++k) { WA[k] = 0.0f; WB[k] = 0.0f; }
    if (loHalf) {
#pragma unroll
        for (int k = 0; k < HSZ; ++k) WA[k] = Whh0[r * HSZ + k];
    } else {
#pragma unroll
        for (int k = 0; k < HSZ; ++k) { WA[k] = Wih1[r * HSZ + k]; WB[k] = Whh1[r * HSZ + k]; }
        base1 = bih1[r] + bhh1[r];
    }
    const float mg  = (p == 2) ? 2.0f : 1.0f;
    const float sg  = (p == 2) ? 2.0f : 1.0f;
    const float tgc = (p == 2) ? -1.0f : 0.0f;

    float c = 0.0f, h = 0.0f;

    for (int t0 = 0; t0 < TLEN; t0 += TCH) {
        const int tcl = min(TCH, TLEN - t0);
        {
            const int tIdx = min(t0 + lane, TLEN - 1);
            const float4* xrow = (const float4*)(x + ((size_t)b * TLEN + tIdx) * ISZ);
#pragma unroll
            for (int grp = 0; grp < 3; ++grp) {
                float acc[8];
#pragma unroll
                for (int rr = 0; rr < 8; ++rr)
                    acc[rr] = bih0[grp * 8 + rr] + bhh0[grp * 8 + rr];
#pragma unroll
                for (int kh = 0; kh < 2; ++kh) {
                    float4 xr[4];
#pragma unroll
                    for (int q = 0; q < 4; ++q) xr[q] = xrow[4 * kh + q];
#pragma unroll
                    for (int rr = 0; rr < 8; ++rr) {
                        const float4* wrow =
                            (const float4*)(Wih0 + (grp * 8 + rr) * ISZ + kh * 16);
#pragma unroll
                        for (int q = 0; q < 4; ++q) {
                            float4 w = wrow[q];
                            acc[rr] += w.x * xr[q].x + w.y * xr[q].y
                                     + w.z * xr[q].z + w.w * xr[q].w;
                        }
                    }
                }
                *(float4*)&xp_lds[lane * XPITCH + 8 * grp] =
                    make_float4(acc[0], acc[1], acc[2], acc[3]);
                *(float4*)&xp_lds[lane * XPITCH + 8 * grp + 4] =
                    make_float4(acc[4], acc[5], acc[6], acc[7]);
            }
        }

        const bool lastChunk = (t0 + TCH >= TLEN);
        const int  iters = tcl + (lastChunk ? 1 : 0);
        float xp_cur = xp_lds[r];
        int   it0 = 0;

        if (t0 == 0) {
            const float g  = loHalf ? xp_cur : base1;
            const float a  = fmaf(sg, fast_sig(mg * g), tgc);
            const float iq = qperm<0x00>(a);
            const float gq = qperm<0xAA>(a);
            const float oq = qperm<0xFF>(a);
            const float cn = iq * gq;
            const float th = fmaf(2.0f, fast_sig(2.0f * cn), -1.0f);
            const float hn = oq * th;
            c = loHalf ? cn : 0.0f;
            h = loHalf ? hn : 0.0f;
            xp_cur = xp_lds[XPITCH + r];
            it0 = 1;
        }

        for (int it = it0; it < iters; ++it) {
            const float h10 = rl(h, 0),  h11 = rl(h, 4),  h12 = rl(h, 8);
            const float h13 = rl(h, 12), h14 = rl(h, 16), h15 = rl(h, 20);
            const float h20 = rl(h, 32), h21 = rl(h, 36), h22 = rl(h, 40);
            const float h23 = rl(h, 44), h24 = rl(h, 48), h25 = rl(h, 52);

            const float xp_nxt = xp_lds[(it + 1) * XPITCH + r];

            const float g0 = loHalf ? xp_cur : base1;
            float a0 = fmaf(WA[0], h10, fmaf(WA[2], h12, fmaf(WA[4], h14, g0)));
            float a1 = fmaf(WA[1], h11, fmaf(WA[3], h13, WA[5] * h15));
            float b0 = fmaf(WB[0], h20, fmaf(WB[2], h22, WB[4] * h24));
            float b1 = fmaf(WB[1], h21, fmaf(WB[3], h23, WB[5] * h25));
            const float g = (a0 + a1) + (b0 + b1);
            const float a = fmaf(sg, fast_sig(mg * g), tgc);

            const float iq = qperm<0x00>(a);
            const float fq = qperm<0x55>(a);
            const float gq = qperm<0xAA>(a);
            const float oq = qperm<0xFF>(a);

            c = fmaf(fq, c, iq * gq);
            const float th = fmaf(2.0f, fast_sig(2.0f * c), -1.0f);
            h = oq * th;

            xp_cur = xp_nxt;
        }
    }

    float s = blin[0];
#pragma unroll
    for (int k = 0; k < HSZ; ++k) s = fmaf(Wlin[k], rl(h, 32 + 4 * k), s);
    if (lane == 0) out[b] = s;
}

extern "C" void kernel_launch(void* const* d_in, const int* in_sizes, int n_in,
                              void* d_out, int out_size, void* d_ws, size_t ws_size,
                              hipStream_t stream) {
    const float* x    = (const float*)d_in[0];
    const float* Wih0 = (const float*)d_in[1];
    const float* Whh0 = (const float*)d_in[2];
    const float* bih0 = (const float*)d_in[3];
    const float* bhh0 = (const float*)d_in[4];
    const float* Wih1 = (const float*)d_in[5];
    const float* Whh1 = (const float*)d_in[6];
    const float* bih1 = (const float*)d_in[7];
    const float* bhh1 = (const float*)d_in[8];
    const float* Wlin = (const float*)d_in[9];
    const float* blin = (const float*)d_in[10];
    float* out = (float*)d_out;

    const size_t need = (size_t)BATCH * XPB * sizeof(float);  // ~81.8 MB
    if (ws_size >= need) {
        float* xp = (float*)d_ws;
        proj_kernel<<<BATCH, 256, 0, stream>>>(x, Wih0, bih0, bhh0, xp);
        scan_kernel<<<BATCH / 4, 256, 0, stream>>>(xp, Whh0, Wih1, Whh1, bih1, bhh1,
                                                   Wlin, blin, out);
    } else {
        lstm_fused<<<BATCH, 64, 0, stream>>>(x, Wih0, Whh0, bih0, bhh0,
                                             Wih1, Whh1, bih1, bhh1,
                                             Wlin, blin, out);
    }
}

// Round 7
// 257.111 us; speedup vs baseline: 1.3091x; 1.1456x over previous
//
#include <hip/hip_runtime.h>

// LSTM_67980742362036: 2-layer LSTM (B=4096, T=200, I=32, H=6) + linear head.
// R7: ONE kernel, ONE loop. One wave per batch (4096 blocks x 64).
//  - Scan core = R4 readlane/DPP form (lane = half*32 + 4*unit + gate).
//  - Projection folded INTO the scan loop: each iter does 12 proj FMAs
//    (3 rows x one K-float4) for the window 64 steps ahead. W lives in LDS
//    (wave-broadcast reads, prefetched 1 step); x streamed via 2-float4
//    rotation (loads issued 4 iters ahead). acc[12] per lane-pair
//    (lane = 2L+o: timestep t=..+L, rows o*12..o*12+11).
//  - xp ring: 64 rows x 25 dwords in LDS. Burst of 12 stores at each
//    32-iter window entry, always one full window ahead of the reader.
//    Single wave => in-wave DS ordering => ZERO barriers.
//  - g-gate's tanh pre-scale (x2) folded into W/bias/burst.
// LDS: ring 6400 B + W 3072 B + bias 96 B = 9568 B -> 16 blocks/CU.

#define TLEN  200
#define ISZ   32
#define HSZ   6
#define RPITCH 25
#define RING_DW (64 * RPITCH)          // 1600
#define WOFF  RING_DW                  // Wih0: 24 rows x 32, pitch 32
#define BOFF  (WOFF + 768)             // bias: 24
#define LDS_DW (BOFF + 24)             // 2392 dwords = 9568 B

__device__ __forceinline__ float fast_sig(float x) {
    return __builtin_amdgcn_rcpf(1.0f + __expf(-x));   // ~1e-7 vs 3.7e-3 thr
}
__device__ __forceinline__ float rl(float v, int l) {
    return __int_as_float(__builtin_amdgcn_readlane(__float_as_int(v), l));
}
template <int CTRL>
__device__ __forceinline__ float qperm(float v) {
    return __int_as_float(__builtin_amdgcn_mov_dpp(__float_as_int(v), CTRL, 0xf, 0xf, true));
}
__device__ __forceinline__ float dot4(float4 w, float4 v) {
    return fmaf(w.x, v.x, fmaf(w.y, v.y, fmaf(w.z, v.z, w.w * v.w)));
}

__global__ __launch_bounds__(64, 4) void lstm_one(
    const float* __restrict__ x,
    const float* __restrict__ Wih0, const float* __restrict__ Whh0,
    const float* __restrict__ bih0, const float* __restrict__ bhh0,
    const float* __restrict__ Wih1, const float* __restrict__ Whh1,
    const float* __restrict__ bih1, const float* __restrict__ bhh1,
    const float* __restrict__ Wlin, const float* __restrict__ blin,
    float* __restrict__ out)
{
    __shared__ float lds[LDS_DW];

    const int lane = threadIdx.x;
    const int b    = blockIdx.x;

    // proj roles: pair (2L, 2L+1) owns timestep base+L; o selects 12 rows.
    const int o = lane & 1;
    const int L = lane >> 1;

    // scan roles: lane = half*32 + 4*unit + gate(i,f,g,o)
    const bool loHalf = (lane < 32);
    const int  p  = lane & 3;
    const int  jq = (lane & 31) >> 2;
    const int  j  = (jq < HSZ) ? jq : 0;
    const int  r  = 6 * p + j;

#define LDSW(ROW, KCQ) (*(const float4*)&lds[WOFF + ((o * 12 + (ROW)) << 5) + ((KCQ) << 2)])

    // ---- stage Wih0 + bias into LDS (in-wave ordering; no barrier) ----
#pragma unroll
    for (int k = 0; k < 13; ++k) {
        const int idx = lane + (k << 6);
        if (idx < 768)      lds[WOFF + idx] = Wih0[idx];
        else if (idx < 792) lds[BOFF + idx - 768] = bih0[idx - 768] + bhh0[idx - 768];
    }

    // ---- scan weights (g-gate x2 pre-fold) ----
    float WA[6], WB[6], base1 = 0.0f, sgc = 1.0f, tgc = 0.0f;
#pragma unroll
    for (int k = 0; k < 6; ++k) { WA[k] = 0.0f; WB[k] = 0.0f; }
    if (loHalf) {
#pragma unroll
        for (int k = 0; k < 6; ++k) WA[k] = Whh0[r * 6 + k];
    } else {
#pragma unroll
        for (int k = 0; k < 6; ++k) { WA[k] = Wih1[r * 6 + k]; WB[k] = Whh1[r * 6 + k]; }
        base1 = bih1[r] + bhh1[r];
    }
    if (p == 2) {   // cell gate: tanh(g) = 2*sig(2g)-1; fold the 2g into weights
#pragma unroll
        for (int k = 0; k < 6; ++k) { WA[k] *= 2.0f; WB[k] *= 2.0f; }
        base1 *= 2.0f; sgc = 2.0f; tgc = -1.0f;
    }

    const float* xb = x + (size_t)b * TLEN * ISZ;

    // ---- prologue: compact-project windows 0,1 (t = 0..63) into ring ----
#pragma unroll
    for (int w01 = 0; w01 < 2; ++w01) {
        const int t = (w01 << 5) + L;
        const float4* xr4 = (const float4*)(xb + t * ISZ);
        float4 xw[8];
#pragma unroll
        for (int q = 0; q < 8; ++q) xw[q] = xr4[q];
        float a0c[12];
#pragma unroll
        for (int jj = 0; jj < 12; ++jj) a0c[jj] = 0.0f;
#pragma unroll
        for (int kc = 0; kc < 8; ++kc)
#pragma unroll
            for (int jj = 0; jj < 12; ++jj)
                a0c[jj] += dot4(LDSW(jj, kc), xw[kc]);
#pragma unroll
        for (int jj = 0; jj < 12; ++jj) {
            float v = a0c[jj] + lds[BOFF + o * 12 + jj];
            if (jj < 6) v = (o == 1) ? v * 2.0f : v;   // g-rows 12..17 pre-x2
            lds[t * RPITCH + o * 12 + jj] = v;
        }
    }

    // ---- spread-projection state (computing window 2 during window 0) ----
    float acc[12];
#pragma unroll
    for (int jj = 0; jj < 12; ++jj) acc[jj] = 0.0f;
    const float* pc = xb + (size_t)min(64 + L, TLEN - 1) * ISZ;  // current target row
    const float* pn = xb + (size_t)min(96 + L, TLEN - 1) * ISZ;  // next target row
    float4 f0, f1;
    f1 = *((const float4*)pc);                         // prime kc0
    float4 Wp0 = LDSW(0, 0), Wp1 = LDSW(1, 0), Wp2 = LDSW(2, 0);  // prime (kc0,rt0)

    float c = 0.0f, h = 0.0f;
    float xp_cur = lds[r];                             // ring slot 0

#define KC_HEAD(KC) do { \
    f0 = f1; \
    const float4* _srcp = ((KC) < 7) ? ((const float4*)pc + (KC) + 1) \
                                     : ((const float4*)pn); \
    f1 = *_srcp; \
} while (0)

#define SPREAD_STEP(RT, KC) do { \
    acc[3*(RT)+0] += dot4(Wp0, f0); \
    acc[3*(RT)+1] += dot4(Wp1, f0); \
    acc[3*(RT)+2] += dot4(Wp2, f0); \
    const int _rtn = ((RT) + 1) & 3; \
    const int _kcn = ((RT) == 3) ? (((KC) + 1) & 7) : (KC); \
    Wp0 = LDSW(3*_rtn + 0, _kcn); \
    Wp1 = LDSW(3*_rtn + 1, _kcn); \
    Wp2 = LDSW(3*_rtn + 2, _kcn); \
} while (0)

#define SCAN_STEP(ITV) do { \
    const float h10=rl(h,0),  h11=rl(h,4),  h12=rl(h,8); \
    const float h13=rl(h,12), h14=rl(h,16), h15=rl(h,20); \
    const float h20=rl(h,32), h21=rl(h,36), h22=rl(h,40); \
    const float h23=rl(h,44), h24=rl(h,48), h25=rl(h,52); \
    const float _xn = lds[(((ITV) + 1) & 63) * RPITCH + r]; \
    const float _g0 = loHalf ? xp_cur : base1; \
    const float _a0 = fmaf(WA[0],h10, fmaf(WA[2],h12, fmaf(WA[4],h14, _g0))); \
    const float _a1 = fmaf(WA[1],h11, fmaf(WA[3],h13, WA[5]*h15)); \
    const float _b0 = fmaf(WB[0],h20, fmaf(WB[2],h22, WB[4]*h24)); \
    const float _b1 = fmaf(WB[1],h21, fmaf(WB[3],h23, WB[5]*h25)); \
    const float _g  = (_a0 + _a1) + (_b0 + _b1); \
    const float _aG = fmaf(sgc, fast_sig(_g), tgc); \
    const float _iq = qperm<0x00>(_aG), _fq = qperm<0x55>(_aG); \
    const float _gq = qperm<0xAA>(_aG), _oq = qperm<0xFF>(_aG); \
    c = fmaf(_fq, c, _iq * _gq); \
    const float _th = fmaf(2.0f, fast_sig(2.0f * c), -1.0f); \
    h = _oq * _th; \
    xp_cur = _xn; \
    if ((ITV) == 200) { \
        float _s = blin[0]; \
        _s = fmaf(Wlin[0], rl(h, 32), _s); \
        _s = fmaf(Wlin[1], rl(h, 36), _s); \
        _s = fmaf(Wlin[2], rl(h, 40), _s); \
        _s = fmaf(Wlin[3], rl(h, 44), _s); \
        _s = fmaf(Wlin[4], rl(h, 48), _s); \
        _s = fmaf(Wlin[5], rl(h, 52), _s); \
        if (lane == 0) out[b] = _s; \
    } \
} while (0)

#define ENTRY(IT0) do { \
    const int _slot = ((IT0) + 32 + L) & 63; \
    _Pragma("unroll") \
    for (int _jj = 0; _jj < 12; ++_jj) { \
        float _v = acc[_jj] + lds[BOFF + o * 12 + _jj]; \
        if (_jj < 6) _v = (o == 1) ? _v * 2.0f : _v; \
        lds[_slot * RPITCH + o * 12 + _jj] = _v; \
        acc[_jj] = 0.0f; \
    } \
    pc = pn; \
    pn = xb + (size_t)min((IT0) + 96 + L, TLEN - 1) * ISZ; \
} while (0)

    // ---- PEEL it=0: kc0 head + spread(0,0) + no-h-dep scan step ----
    KC_HEAD(0);
    SPREAD_STEP(0, 0);
    {
        const float g  = loHalf ? xp_cur : base1;
        const float aG = fmaf(sgc, fast_sig(g), tgc);
        const float iq = qperm<0x00>(aG), gq = qperm<0xAA>(aG), oq = qperm<0xFF>(aG);
        const float cn = iq * gq;                       // f*c0 = 0
        const float th = fmaf(2.0f, fast_sig(2.0f * cn), -1.0f);
        c = loHalf ? cn : 0.0f;
        h = loHalf ? (oq * th) : 0.0f;                  // L1 phantom stays 0
        xp_cur = lds[RPITCH + r];                       // slot 1
    }

    // ---- window 0 remainder: kc0 rt1..3 (it=1..3), then kc=1..7 ----
    SPREAD_STEP(1, 0); SCAN_STEP(1);
    SPREAD_STEP(2, 0); SCAN_STEP(2);
    SPREAD_STEP(3, 0); SCAN_STEP(3);
    for (int kc = 1; kc < 8; ++kc) {
        KC_HEAD(kc);
        const int itb = kc << 2;
        SPREAD_STEP(0, kc); SCAN_STEP(itb + 0);
        SPREAD_STEP(1, kc); SCAN_STEP(itb + 1);
        SPREAD_STEP(2, kc); SCAN_STEP(itb + 2);
        SPREAD_STEP(3, kc); SCAN_STEP(itb + 3);
    }

    // ---- windows 1..6 (entries at it0=32w; tail breaks after it=203) ----
    for (int w = 1; w < 7; ++w) {
        const int it0 = w << 5;
        ENTRY(it0);
        for (int kc = 0; kc < 8; ++kc) {
            const int itb = it0 + (kc << 2);
            if (itb > 200) break;
            KC_HEAD(kc);
            SPREAD_STEP(0, kc); SCAN_STEP(itb + 0);
            SPREAD_STEP(1, kc); SCAN_STEP(itb + 1);
            SPREAD_STEP(2, kc); SCAN_STEP(itb + 2);
            SPREAD_STEP(3, kc); SCAN_STEP(itb + 3);
        }
    }

#undef LDSW
#undef KC_HEAD
#undef SPREAD_STEP
#undef SCAN_STEP
#undef ENTRY
}

extern "C" void kernel_launch(void* const* d_in, const int* in_sizes, int n_in,
                              void* d_out, int out_size, void* d_ws, size_t ws_size,
                              hipStream_t stream) {
    const float* x    = (const float*)d_in[0];
    const float* Wih0 = (const float*)d_in[1];
    const float* Whh0 = (const float*)d_in[2];
    const float* bih0 = (const float*)d_in[3];
    const float* bhh0 = (const float*)d_in[4];
    const float* Wih1 = (const float*)d_in[5];
    const float* Whh1 = (const float*)d_in[6];
    const float* bih1 = (const float*)d_in[7];
    const float* bhh1 = (const float*)d_in[8];
    const float* Wlin = (const float*)d_in[9];
    const float* blin = (const float*)d_in[10];
    float* out = (float*)d_out;

    lstm_one<<<4096, 64, 0, stream>>>(x, Wih0, Whh0, bih0, bhh0,
                                      Wih1, Whh1, bih1, bhh1,
                                      Wlin, blin, out);
}

// Round 8
// 251.736 us; speedup vs baseline: 1.3370x; 1.0214x over previous
//
#include <hip/hip_runtime.h>

// LSTM_67980742362036: 2-layer LSTM (B=4096, T=200, I=32, H=6) + linear head.
// R8 = R7 structure with two fixes:
//  - __launch_bounds__(64) ONLY. Evidence across rounds: the 2nd arg (",4")
//    caps the allocator at 64 VGPRs -> 4 KB/block scratch spills threaded
//    through the serial loop (R7 WRITE_SIZE 16.5 MB). Plain (64) gave
//    VGPR=112, zero scratch in R4.
//  - W LDS pitch 32 -> 36 dwords: the per-iter ds_read_b128 W reads use two
//    addresses (o=0 vs o=1 rows) 12 rows apart; 12*32 % 32 == 0 (same banks,
//    1.44e7 conflict cycles), 12*36 % 32 == 16 (disjoint banks).
// Structure: one wave per batch; projection folded into the scan loop
// (12 proj FMAs/iter toward the window 64 steps ahead); xp ring in LDS;
// zero barriers (single wave).

#define TLEN  200
#define ISZ   32
#define HSZ   6
#define RPITCH 25
#define WPITCH 36                      // W row pitch in dwords (bank-split fix)
#define RING_DW (64 * RPITCH)          // 1600
#define WOFF  RING_DW                  // Wih0: 24 rows x WPITCH
#define BOFF  (WOFF + 24 * WPITCH)     // bias: 24
#define LDS_DW (BOFF + 24)             // 2488 dwords = 9952 B (<= 10240)

__device__ __forceinline__ float fast_sig(float x) {
    return __builtin_amdgcn_rcpf(1.0f + __expf(-x));   // ~1e-7 vs 3.7e-3 thr
}
__device__ __forceinline__ float rl(float v, int l) {
    return __int_as_float(__builtin_amdgcn_readlane(__float_as_int(v), l));
}
template <int CTRL>
__device__ __forceinline__ float qperm(float v) {
    return __int_as_float(__builtin_amdgcn_mov_dpp(__float_as_int(v), CTRL, 0xf, 0xf, true));
}
__device__ __forceinline__ float dot4(float4 w, float4 v) {
    return fmaf(w.x, v.x, fmaf(w.y, v.y, fmaf(w.z, v.z, w.w * v.w)));
}

__global__ __launch_bounds__(64) void lstm_one(
    const float* __restrict__ x,
    const float* __restrict__ Wih0, const float* __restrict__ Whh0,
    const float* __restrict__ bih0, const float* __restrict__ bhh0,
    const float* __restrict__ Wih1, const float* __restrict__ Whh1,
    const float* __restrict__ bih1, const float* __restrict__ bhh1,
    const float* __restrict__ Wlin, const float* __restrict__ blin,
    float* __restrict__ out)
{
    __shared__ float lds[LDS_DW];

    const int lane = threadIdx.x;
    const int b    = blockIdx.x;

    // proj roles: pair (2L, 2L+1) owns timestep base+L; o selects 12 rows.
    const int o = lane & 1;
    const int L = lane >> 1;

    // scan roles: lane = half*32 + 4*unit + gate(i,f,g,o)
    const bool loHalf = (lane < 32);
    const int  p  = lane & 3;
    const int  jq = (lane & 31) >> 2;
    const int  j  = (jq < HSZ) ? jq : 0;
    const int  r  = 6 * p + j;

#define LDSW(ROW, KCQ) (*(const float4*)&lds[WOFF + (o * 12 + (ROW)) * WPITCH + ((KCQ) << 2)])

    // ---- stage Wih0 + bias into LDS (in-wave ordering; no barrier) ----
#pragma unroll
    for (int k = 0; k < 13; ++k) {
        const int idx = lane + (k << 6);
        if (idx < 768) {
            const int row = idx >> 5, kk = idx & 31;
            lds[WOFF + row * WPITCH + kk] = Wih0[idx];
        } else if (idx < 792) {
            lds[BOFF + idx - 768] = bih0[idx - 768] + bhh0[idx - 768];
        }
    }

    // ---- scan weights (g-gate x2 pre-fold) ----
    float WA[6], WB[6], base1 = 0.0f, sgc = 1.0f, tgc = 0.0f;
#pragma unroll
    for (int k = 0; k < 6; ++k) { WA[k] = 0.0f; WB[k] = 0.0f; }
    if (loHalf) {
#pragma unroll
        for (int k = 0; k < 6; ++k) WA[k] = Whh0[r * 6 + k];
    } else {
#pragma unroll
        for (int k = 0; k < 6; ++k) { WA[k] = Wih1[r * 6 + k]; WB[k] = Whh1[r * 6 + k]; }
        base1 = bih1[r] + bhh1[r];
    }
    if (p == 2) {   // cell gate: tanh(g) = 2*sig(2g)-1; fold the 2g into weights
#pragma unroll
        for (int k = 0; k < 6; ++k) { WA[k] *= 2.0f; WB[k] *= 2.0f; }
        base1 *= 2.0f; sgc = 2.0f; tgc = -1.0f;
    }

    const float* xb = x + (size_t)b * TLEN * ISZ;

    // ---- prologue: compact-project windows 0,1 (t = 0..63) into ring ----
#pragma unroll
    for (int w01 = 0; w01 < 2; ++w01) {
        const int t = (w01 << 5) + L;
        const float4* xr4 = (const float4*)(xb + t * ISZ);
        float4 xw[8];
#pragma unroll
        for (int q = 0; q < 8; ++q) xw[q] = xr4[q];
        float a0c[12];
#pragma unroll
        for (int jj = 0; jj < 12; ++jj) a0c[jj] = 0.0f;
#pragma unroll
        for (int kc = 0; kc < 8; ++kc)
#pragma unroll
            for (int jj = 0; jj < 12; ++jj)
                a0c[jj] += dot4(LDSW(jj, kc), xw[kc]);
#pragma unroll
        for (int jj = 0; jj < 12; ++jj) {
            float v = a0c[jj] + lds[BOFF + o * 12 + jj];
            if (jj < 6) v = (o == 1) ? v * 2.0f : v;   // g-rows 12..17 pre-x2
            lds[t * RPITCH + o * 12 + jj] = v;
        }
    }

    // ---- spread-projection state (computing window 2 during window 0) ----
    float acc[12];
#pragma unroll
    for (int jj = 0; jj < 12; ++jj) acc[jj] = 0.0f;
    const float* pc = xb + (size_t)min(64 + L, TLEN - 1) * ISZ;  // current target row
    const float* pn = xb + (size_t)min(96 + L, TLEN - 1) * ISZ;  // next target row
    float4 f0, f1;
    f1 = *((const float4*)pc);                         // prime kc0
    float4 Wp0 = LDSW(0, 0), Wp1 = LDSW(1, 0), Wp2 = LDSW(2, 0);  // prime (kc0,rt0)

    float c = 0.0f, h = 0.0f;
    float xp_cur = lds[r];                             // ring slot 0

#define KC_HEAD(KC) do { \
    f0 = f1; \
    const float4* _srcp = ((KC) < 7) ? ((const float4*)pc + (KC) + 1) \
                                     : ((const float4*)pn); \
    f1 = *_srcp; \
} while (0)

#define SPREAD_STEP(RT, KC) do { \
    acc[3*(RT)+0] += dot4(Wp0, f0); \
    acc[3*(RT)+1] += dot4(Wp1, f0); \
    acc[3*(RT)+2] += dot4(Wp2, f0); \
    const int _rtn = ((RT) + 1) & 3; \
    const int _kcn = ((RT) == 3) ? (((KC) + 1) & 7) : (KC); \
    Wp0 = LDSW(3*_rtn + 0, _kcn); \
    Wp1 = LDSW(3*_rtn + 1, _kcn); \
    Wp2 = LDSW(3*_rtn + 2, _kcn); \
} while (0)

#define SCAN_STEP(ITV) do { \
    const float h10=rl(h,0),  h11=rl(h,4),  h12=rl(h,8); \
    const float h13=rl(h,12), h14=rl(h,16), h15=rl(h,20); \
    const float h20=rl(h,32), h21=rl(h,36), h22=rl(h,40); \
    const float h23=rl(h,44), h24=rl(h,48), h25=rl(h,52); \
    const float _xn = lds[(((ITV) + 1) & 63) * RPITCH + r]; \
    const float _g0 = loHalf ? xp_cur : base1; \
    const float _a0 = fmaf(WA[0],h10, fmaf(WA[2],h12, fmaf(WA[4],h14, _g0))); \
    const float _a1 = fmaf(WA[1],h11, fmaf(WA[3],h13, WA[5]*h15)); \
    const float _b0 = fmaf(WB[0],h20, fmaf(WB[2],h22, WB[4]*h24)); \
    const float _b1 = fmaf(WB[1],h21, fmaf(WB[3],h23, WB[5]*h25)); \
    const float _g  = (_a0 + _a1) + (_b0 + _b1); \
    const float _aG = fmaf(sgc, fast_sig(_g), tgc); \
    const float _iq = qperm<0x00>(_aG), _fq = qperm<0x55>(_aG); \
    const float _gq = qperm<0xAA>(_aG), _oq = qperm<0xFF>(_aG); \
    c = fmaf(_fq, c, _iq * _gq); \
    const float _th = fmaf(2.0f, fast_sig(2.0f * c), -1.0f); \
    h = _oq * _th; \
    xp_cur = _xn; \
    if ((ITV) == 200) { \
        float _s = blin[0]; \
        _s = fmaf(Wlin[0], rl(h, 32), _s); \
        _s = fmaf(Wlin[1], rl(h, 36), _s); \
        _s = fmaf(Wlin[2], rl(h, 40), _s); \
        _s = fmaf(Wlin[3], rl(h, 44), _s); \
        _s = fmaf(Wlin[4], rl(h, 48), _s); \
        _s = fmaf(Wlin[5], rl(h, 52), _s); \
        if (lane == 0) out[b] = _s; \
    } \
} while (0)

#define ENTRY(IT0) do { \
    const int _slot = ((IT0) + 32 + L) & 63; \
    _Pragma("unroll") \
    for (int _jj = 0; _jj < 12; ++_jj) { \
        float _v = acc[_jj] + lds[BOFF + o * 12 + _jj]; \
        if (_jj < 6) _v = (o == 1) ? _v * 2.0f : _v; \
        lds[_slot * RPITCH + o * 12 + _jj] = _v; \
        acc[_jj] = 0.0f; \
    } \
    pc = pn; \
    pn = xb + (size_t)min((IT0) + 96 + L, TLEN - 1) * ISZ; \
} while (0)

    // ---- PEEL it=0: kc0 head + spread(0,0) + no-h-dep scan step ----
    KC_HEAD(0);
    SPREAD_STEP(0, 0);
    {
        const float g  = loHalf ? xp_cur : base1;
        const float aG = fmaf(sgc, fast_sig(g), tgc);
        const float iq = qperm<0x00>(aG), gq = qperm<0xAA>(aG), oq = qperm<0xFF>(aG);
        const float cn = iq * gq;                       // f*c0 = 0
        const float th = fmaf(2.0f, fast_sig(2.0f * cn), -1.0f);
        c = loHalf ? cn : 0.0f;
        h = loHalf ? (oq * th) : 0.0f;                  // L1 phantom stays 0
        xp_cur = lds[RPITCH + r];                       // slot 1
    }

    // ---- window 0 remainder: kc0 rt1..3 (it=1..3), then kc=1..7 ----
    SPREAD_STEP(1, 0); SCAN_STEP(1);
    SPREAD_STEP(2, 0); SCAN_STEP(2);
    SPREAD_STEP(3, 0); SCAN_STEP(3);
    for (int kc = 1; kc < 8; ++kc) {
        KC_HEAD(kc);
        const int itb = kc << 2;
        SPREAD_STEP(0, kc); SCAN_STEP(itb + 0);
        SPREAD_STEP(1, kc); SCAN_STEP(itb + 1);
        SPREAD_STEP(2, kc); SCAN_STEP(itb + 2);
        SPREAD_STEP(3, kc); SCAN_STEP(itb + 3);
    }

    // ---- windows 1..6 (entries at it0=32w; tail breaks after it=203) ----
    for (int w = 1; w < 7; ++w) {
        const int it0 = w << 5;
        ENTRY(it0);
        for (int kc = 0; kc < 8; ++kc) {
            const int itb = it0 + (kc << 2);
            if (itb > 200) break;
            KC_HEAD(kc);
            SPREAD_STEP(0, kc); SCAN_STEP(itb + 0);
            SPREAD_STEP(1, kc); SCAN_STEP(itb + 1);
            SPREAD_STEP(2, kc); SCAN_STEP(itb + 2);
            SPREAD_STEP(3, kc); SCAN_STEP(itb + 3);
        }
    }

#undef LDSW
#undef KC_HEAD
#undef SPREAD_STEP
#undef SCAN_STEP
#undef ENTRY
}

extern "C" void kernel_launch(void* const* d_in, const int* in_sizes, int n_in,
                              void* d_out, int out_size, void* d_ws, size_t ws_size,
                              hipStream_t stream) {
    const float* x    = (const float*)d_in[0];
    const float* Wih0 = (const float*)d_in[1];
    const float* Whh0 = (const float*)d_in[2];
    const float* bih0 = (const float*)d_in[3];
    const float* bhh0 = (const float*)d_in[4];
    const float* Wih1 = (const float*)d_in[5];
    const float* Whh1 = (const float*)d_in[6];
    const float* bih1 = (const float*)d_in[7];
    const float* bhh1 = (const float*)d_in[8];
    const float* Wlin = (const float*)d_in[9];
    const float* blin = (const float*)d_in[10];
    float* out = (float*)d_out;

    lstm_one<<<4096, 64, 0, stream>>>(x, Wih0, Whh0, bih0, bhh0,
                                      Wih1, Whh1, bih1, bhh1,
                                      Wlin, blin, out);
}